// Round 2
// baseline (25325.200 us; speedup 1.0000x reference)
//
#include <hip/hip_runtime.h>

#define B_ 16
#define S_ 256
#define H_ 768
#define NH_ 12
#define DH_ 64
#define L_ 12
#define FF_ 3072
#define T_ 9
#define NTOK (B_*S_)

// ---------------- embedding + LN ----------------
__global__ __launch_bounds__(256) void k_embed_ln(
    const int* __restrict__ ids, const float* __restrict__ wemb,
    const float* __restrict__ pemb, const float* __restrict__ temb,
    const float* __restrict__ g, const float* __restrict__ b,
    float* __restrict__ out)
{
    int tok = blockIdx.x;
    int s = tok & (S_ - 1);
    int id = ids[tok];
    __shared__ float buf[H_];
    __shared__ float red[256];
    int tid = threadIdx.x;
    float acc = 0.f;
    for (int i = tid; i < H_; i += 256) {
        float v = wemb[(size_t)id * H_ + i] + pemb[(size_t)s * H_ + i] + temb[i];
        buf[i] = v; acc += v;
    }
    red[tid] = acc; __syncthreads();
    for (int o = 128; o > 0; o >>= 1) { if (tid < o) red[tid] += red[tid + o]; __syncthreads(); }
    float mean = red[0] * (1.0f / H_);
    __syncthreads();
    float vs = 0.f;
    for (int i = tid; i < H_; i += 256) { float d = buf[i] - mean; vs += d * d; }
    red[tid] = vs; __syncthreads();
    for (int o = 128; o > 0; o >>= 1) { if (tid < o) red[tid] += red[tid + o]; __syncthreads(); }
    float inv = 1.0f / sqrtf(red[0] * (1.0f / H_) + 1e-12f);
    for (int i = tid; i < H_; i += 256)
        out[(size_t)tok * H_ + i] = (buf[i] - mean) * inv * g[i] + b[i];
}

// ---------------- residual + LN ----------------
__global__ __launch_bounds__(256) void k_residual_ln(
    const float* __restrict__ x, const float* __restrict__ res,
    const float* __restrict__ g, const float* __restrict__ b,
    float* __restrict__ out)
{
    int tok = blockIdx.x;
    __shared__ float buf[H_];
    __shared__ float red[256];
    const float* xr = x + (size_t)tok * H_;
    const float* rr = res + (size_t)tok * H_;
    int tid = threadIdx.x;
    float acc = 0.f;
    for (int i = tid; i < H_; i += 256) { float v = xr[i] + rr[i]; buf[i] = v; acc += v; }
    red[tid] = acc; __syncthreads();
    for (int o = 128; o > 0; o >>= 1) { if (tid < o) red[tid] += red[tid + o]; __syncthreads(); }
    float mean = red[0] * (1.0f / H_);
    __syncthreads();
    float vs = 0.f;
    for (int i = tid; i < H_; i += 256) { float d = buf[i] - mean; vs += d * d; }
    red[tid] = vs; __syncthreads();
    for (int o = 128; o > 0; o >>= 1) { if (tid < o) red[tid] += red[tid + o]; __syncthreads(); }
    float inv = 1.0f / sqrtf(red[0] * (1.0f / H_) + 1e-12f);
    for (int i = tid; i < H_; i += 256)
        out[(size_t)tok * H_ + i] = (buf[i] - mean) * inv * g[i] + b[i];
}

// ---------------- fp32 GEMM: C = A(MxK) @ W(KxN) + bias, optional exact GELU ----------------
// 128x128 tile, 256 threads, each 8x8, K-tile 8
__global__ __launch_bounds__(256) void k_gemm(
    const float* __restrict__ A, const float* __restrict__ W,
    const float* __restrict__ bias, float* __restrict__ C,
    int M, int N, int K, int act)
{
    __shared__ float As[8][129];   // [k][m]
    __shared__ float Bs[8][129];   // [k][n]
    int tid = threadIdx.x;
    int m0 = blockIdx.y * 128;
    int n0 = blockIdx.x * 128;
    int tx = tid & 15, ty = tid >> 4;
    float accv[8][8];
    #pragma unroll
    for (int i = 0; i < 8; i++)
        #pragma unroll
        for (int j = 0; j < 8; j++) accv[i][j] = 0.f;

    for (int k0 = 0; k0 < K; k0 += 8) {
        #pragma unroll
        for (int i = 0; i < 4; i++) {
            int e = tid + 256 * i;
            int r = e >> 3, c = e & 7;
            As[c][r] = A[(size_t)(m0 + r) * K + k0 + c];
        }
        #pragma unroll
        for (int i = 0; i < 4; i++) {
            int e = tid + 256 * i;
            int r = e >> 7, c = e & 127;
            Bs[r][c] = W[(size_t)(k0 + r) * N + n0 + c];
        }
        __syncthreads();
        #pragma unroll
        for (int kk = 0; kk < 8; kk++) {
            float a[8], bz[8];
            #pragma unroll
            for (int i = 0; i < 8; i++) a[i] = As[kk][ty + 16 * i];
            #pragma unroll
            for (int j = 0; j < 8; j++) bz[j] = Bs[kk][tx + 16 * j];
            #pragma unroll
            for (int i = 0; i < 8; i++)
                #pragma unroll
                for (int j = 0; j < 8; j++)
                    accv[i][j] = fmaf(a[i], bz[j], accv[i][j]);
        }
        __syncthreads();
    }
    #pragma unroll
    for (int i = 0; i < 8; i++) {
        int m = m0 + ty + 16 * i;
        #pragma unroll
        for (int j = 0; j < 8; j++) {
            int n = n0 + tx + 16 * j;
            float v = accv[i][j] + bias[n];
            if (act == 1) v = 0.5f * v * (1.0f + erff(v * 0.70710678118654752f));
            C[(size_t)m * N + n] = v;
        }
    }
}

// ---------------- attention scores + softmax ----------------
// block per (b, h, q): 256 threads, one key each
__global__ __launch_bounds__(256) void k_attn_scores(
    const float* __restrict__ Q, const float* __restrict__ Kb,
    const int* __restrict__ amask, float* __restrict__ att)
{
    int idx = blockIdx.x;
    int qpos = idx & (S_ - 1);
    int h = (idx >> 8) % NH_;
    int b = idx / (NH_ * S_);
    __shared__ float qv[DH_];
    __shared__ float red[256];
    int tid = threadIdx.x;
    const float* qp = Q + ((size_t)(b * S_ + qpos)) * H_ + h * DH_;
    if (tid < DH_) qv[tid] = qp[tid];
    __syncthreads();
    const float* kp = Kb + ((size_t)(b * S_ + tid)) * H_ + h * DH_;
    float dot = 0.f;
    #pragma unroll 8
    for (int d = 0; d < DH_; d++) dot = fmaf(qv[d], kp[d], dot);
    float sbias = (amask[b * S_ + tid] == 0) ? -1e9f : 0.f;
    float sc = dot * 0.125f + sbias;
    red[tid] = sc; __syncthreads();
    for (int o = 128; o > 0; o >>= 1) { if (tid < o) red[tid] = fmaxf(red[tid], red[tid + o]); __syncthreads(); }
    float mx = red[0]; __syncthreads();
    float e = expf(sc - mx);
    red[tid] = e; __syncthreads();
    for (int o = 128; o > 0; o >>= 1) { if (tid < o) red[tid] += red[tid + o]; __syncthreads(); }
    float p = e / red[0];
    att[((size_t)((b * NH_ + h) * S_ + qpos)) * S_ + tid] = p;
}

// ---------------- ctx = att @ V ----------------
// block per (b, h, q): 64 threads, one d each
__global__ __launch_bounds__(64) void k_attn_ctx(
    const float* __restrict__ att, const float* __restrict__ V,
    float* __restrict__ ctx)
{
    int idx = blockIdx.x;
    int qpos = idx & (S_ - 1);
    int h = (idx >> 8) % NH_;
    int b = idx / (NH_ * S_);
    int d = threadIdx.x;
    const float* ap = att + ((size_t)((b * NH_ + h) * S_ + qpos)) * S_;
    const float* vp = V + ((size_t)(b * S_)) * H_ + h * DH_ + d;
    float s = 0.f;
    #pragma unroll 4
    for (int k = 0; k < S_; k++) s = fmaf(ap[k], vp[(size_t)k * H_], s);
    ctx[((size_t)(b * S_ + qpos)) * H_ + h * DH_ + d] = s;
}

// ---------------- classifier: logits = h @ cls_W(768x9) + cls_b ----------------
__global__ __launch_bounds__(64) void k_classifier(
    const float* __restrict__ Hs, const float* __restrict__ Wc,
    const float* __restrict__ bc, float* __restrict__ logits)
{
    int tok = blockIdx.x;
    int lane = threadIdx.x;
    const float* hr = Hs + (size_t)tok * H_;
    float acc[T_];
    #pragma unroll
    for (int j = 0; j < T_; j++) acc[j] = 0.f;
    for (int k = lane; k < H_; k += 64) {
        float hv = hr[k];
        const float* wr = Wc + (size_t)k * T_;
        #pragma unroll
        for (int j = 0; j < T_; j++) acc[j] = fmaf(hv, wr[j], acc[j]);
    }
    #pragma unroll
    for (int j = 0; j < T_; j++) {
        float v = acc[j];
        for (int o = 32; o > 0; o >>= 1) v += __shfl_down(v, o);
        if (lane == 0) logits[(size_t)tok * T_ + j] = v + bc[j];
    }
}

// ---------------- CRF negative log-likelihood (loss) ----------------
// single block, 256 threads; batches in parallel (16*9 = 144 active lanes)
__global__ __launch_bounds__(256) void k_crf_loss(
    const float* __restrict__ logits, const int* __restrict__ amask,
    const int* __restrict__ labels, const float* __restrict__ start,
    const float* __restrict__ endv, const float* __restrict__ trans,
    float* __restrict__ out_loss)
{
    __shared__ float score[B_][T_];
    __shared__ float nxt[B_][T_];
    __shared__ float res[B_];   // den - num
    __shared__ int len_s[B_];
    int tid = threadIdx.x;
    if (tid < B_) {
        int l = 0;
        for (int s = 0; s < S_; s++) l += amask[tid * S_ + s];
        len_s[tid] = l;
    }
    __syncthreads();
    int b = tid / T_, j = tid % T_;
    if (tid < B_ * T_)
        score[b][j] = start[j] + logits[((size_t)(b * S_ + 1)) * T_ + j];
    __syncthreads();
    // forward recursion over s = 2..255
    for (int s = 2; s < S_; s++) {
        if (tid < B_ * T_) {
            int len = len_s[b];
            int mt = (amask[b * S_ + s] != 0) && (s != len - 1);
            float mx = -1e30f;
            #pragma unroll
            for (int i = 0; i < T_; i++) mx = fmaxf(mx, score[b][i] + trans[i * T_ + j]);
            float sum = 0.f;
            #pragma unroll
            for (int i = 0; i < T_; i++) sum += expf(score[b][i] + trans[i * T_ + j] - mx);
            float lse = mx + logf(sum) + logits[((size_t)(b * S_ + s)) * T_ + j];
            nxt[b][j] = mt ? lse : score[b][j];
        }
        __syncthreads();
        if (tid < B_ * T_) score[b][j] = nxt[b][j];
        __syncthreads();
    }
    // numerator + denominator per batch
    if (tid < B_) {
        int bb = tid;
        int len = len_s[bb];
        int s1m = (amask[bb * S_ + 1] != 0) && (1 != len - 1);
        int tp = s1m ? labels[bb * S_ + 1] : 0;
        int msum = s1m ? 1 : 0;
        float num = start[tp] + logits[((size_t)(bb * S_ + 1)) * T_ + tp];
        for (int s = 2; s < S_; s++) {
            int mk = (amask[bb * S_ + s] != 0) && (s != len - 1);
            int tc = mk ? labels[bb * S_ + s] : 0;
            if (mk) {
                num += trans[tp * T_ + tc] + logits[((size_t)(bb * S_ + s)) * T_ + tc];
                msum++;
            }
            tp = tc;
        }
        int ls = msum;  // absolute s-index of last masked tag
        int mkl = (amask[bb * S_ + ls] != 0) && (ls != len - 1) && (ls > 0);
        int last_tag = mkl ? labels[bb * S_ + ls] : 0;
        num += endv[last_tag];
        // den = logsumexp_j(score[bb][j] + end[j])
        float mx = -1e30f;
        #pragma unroll
        for (int jj = 0; jj < T_; jj++) mx = fmaxf(mx, score[bb][jj] + endv[jj]);
        float sum = 0.f;
        #pragma unroll
        for (int jj = 0; jj < T_; jj++) sum += expf(score[bb][jj] + endv[jj] - mx);
        float den = mx + logf(sum);
        res[bb] = den - num;
    }
    __syncthreads();
    if (tid == 0) {
        float tot = 0.f;
        for (int bb = 0; bb < B_; bb++) tot += res[bb];
        out_loss[0] = tot;
    }
}

// ---------------- Viterbi decode ----------------
__global__ __launch_bounds__(64) void k_viterbi(
    const float* __restrict__ logits, const float* __restrict__ start,
    const float* __restrict__ endv, const float* __restrict__ trans,
    float* __restrict__ tags_out)
{
    int b = blockIdx.x;
    int tid = threadIdx.x;
    __shared__ float score[T_], nxt[T_];
    __shared__ unsigned char hist[S_ - 1][T_];
    if (tid < T_) score[tid] = start[tid] + logits[((size_t)(b * S_)) * T_ + tid];
    __syncthreads();
    for (int t = 1; t < S_; t++) {
        if (tid < T_) {
            int j = tid;
            float best = -1e30f; int bi = 0;
            #pragma unroll
            for (int i = 0; i < T_; i++) {
                float c = score[i] + trans[i * T_ + j];
                if (c > best) { best = c; bi = i; }
            }
            nxt[j] = best + logits[((size_t)(b * S_ + t)) * T_ + j];
            hist[t - 1][j] = (unsigned char)bi;
        }
        __syncthreads();
        if (tid < T_) score[tid] = nxt[tid];
        __syncthreads();
    }
    if (tid == 0) {
        float best = -1e30f; int last = 0;
        for (int j = 0; j < T_; j++) {
            float c = score[j] + endv[j];
            if (c > best) { best = c; last = j; }
        }
        tags_out[b * S_ + (S_ - 1)] = (float)last;
        int cur = last;
        for (int t = S_ - 2; t >= 0; t--) {
            cur = hist[t][cur];
            tags_out[b * S_ + t] = (float)cur;
        }
    }
}

// ---------------- driver ----------------
extern "C" void kernel_launch(void* const* d_in, const int* in_sizes, int n_in,
                              void* d_out, int out_size, void* d_ws, size_t ws_size,
                              hipStream_t stream)
{
    const int*   input_ids = (const int*)d_in[0];
    const int*   amask     = (const int*)d_in[1];
    const int*   labels    = (const int*)d_in[2];
    const float* word_emb  = (const float*)d_in[3];
    const float* pos_emb   = (const float*)d_in[4];
    const float* type_emb  = (const float*)d_in[5];
    const float* emb_g     = (const float*)d_in[6];
    const float* emb_b     = (const float*)d_in[7];
    const float* lWq = (const float*)d_in[8];
    const float* lbq = (const float*)d_in[9];
    const float* lWk = (const float*)d_in[10];
    const float* lbk = (const float*)d_in[11];
    const float* lWv = (const float*)d_in[12];
    const float* lbv = (const float*)d_in[13];
    const float* lWo = (const float*)d_in[14];
    const float* lbo = (const float*)d_in[15];
    const float* lg1 = (const float*)d_in[16];
    const float* lb1 = (const float*)d_in[17];
    const float* lWi = (const float*)d_in[18];
    const float* lbi = (const float*)d_in[19];
    const float* lWf = (const float*)d_in[20];
    const float* lbf = (const float*)d_in[21];
    const float* lg2 = (const float*)d_in[22];
    const float* lb2 = (const float*)d_in[23];
    const float* cls_W = (const float*)d_in[24];
    const float* cls_b = (const float*)d_in[25];
    const float* crf_start = (const float*)d_in[26];
    const float* crf_end   = (const float*)d_in[27];
    const float* crf_trans = (const float*)d_in[28];

    float* out = (float*)d_out;

    float* ws = (float*)d_ws;
    size_t off = 0;
    auto alloc = [&](size_t n) { float* p = ws + off; off += n; return p; };
    float* h    = alloc((size_t)NTOK * H_);
    float* q    = alloc((size_t)NTOK * H_);
    float* kbuf = alloc((size_t)NTOK * H_);
    float* v    = alloc((size_t)NTOK * H_);
    float* ctx  = alloc((size_t)NTOK * H_);
    float* tmp  = alloc((size_t)NTOK * H_);
    float* big  = alloc((size_t)NTOK * FF_);  // shared: att scores (B*NH*S*S) and FF activations (both 12.58M floats)
    float* logits = alloc((size_t)NTOK * T_);

    k_embed_ln<<<NTOK, 256, 0, stream>>>(input_ids, word_emb, pos_emb, type_emb, emb_g, emb_b, h);

    dim3 gHH(H_ / 128, NTOK / 128);
    dim3 gFF1(FF_ / 128, NTOK / 128);
    dim3 gFF2(H_ / 128, NTOK / 128);

    for (int l = 0; l < L_; l++) {
        const float* Wq = lWq + (size_t)l * H_ * H_;
        const float* bq = lbq + (size_t)l * H_;
        const float* Wk = lWk + (size_t)l * H_ * H_;
        const float* bk = lbk + (size_t)l * H_;
        const float* Wv = lWv + (size_t)l * H_ * H_;
        const float* bv = lbv + (size_t)l * H_;
        const float* Wo = lWo + (size_t)l * H_ * H_;
        const float* bo = lbo + (size_t)l * H_;
        const float* g1 = lg1 + (size_t)l * H_;
        const float* b1 = lb1 + (size_t)l * H_;
        const float* Wi = lWi + (size_t)l * H_ * FF_;
        const float* bi = lbi + (size_t)l * FF_;
        const float* Wf = lWf + (size_t)l * FF_ * H_;
        const float* bf = lbf + (size_t)l * H_;
        const float* g2 = lg2 + (size_t)l * H_;
        const float* b2 = lb2 + (size_t)l * H_;

        k_gemm<<<gHH, 256, 0, stream>>>(h, Wq, bq, q,    NTOK, H_, H_, 0);
        k_gemm<<<gHH, 256, 0, stream>>>(h, Wk, bk, kbuf, NTOK, H_, H_, 0);
        k_gemm<<<gHH, 256, 0, stream>>>(h, Wv, bv, v,    NTOK, H_, H_, 0);

        k_attn_scores<<<B_ * NH_ * S_, 256, 0, stream>>>(q, kbuf, amask, big);
        k_attn_ctx<<<B_ * NH_ * S_, 64, 0, stream>>>(big, v, ctx);

        k_gemm<<<gHH, 256, 0, stream>>>(ctx, Wo, bo, tmp, NTOK, H_, H_, 0);
        k_residual_ln<<<NTOK, 256, 0, stream>>>(tmp, h, g1, b1, h);

        k_gemm<<<gFF1, 256, 0, stream>>>(h, Wi, bi, big, NTOK, FF_, H_, 1);
        k_gemm<<<gFF2, 256, 0, stream>>>(big, Wf, bf, tmp, NTOK, H_, FF_, 0);
        k_residual_ln<<<NTOK, 256, 0, stream>>>(tmp, h, g2, b2, h);
    }

    k_classifier<<<NTOK, 64, 0, stream>>>(h, cls_W, cls_b, logits);
    k_crf_loss<<<1, 256, 0, stream>>>(logits, amask, labels, crf_start, crf_end, crf_trans, out);
    k_viterbi<<<B_, 64, 0, stream>>>(logits, crf_start, crf_end, crf_trans, out + 1);
}

// Round 3
// 13459.702 us; speedup vs baseline: 1.8816x; 1.8816x over previous
//
#include <hip/hip_runtime.h>

#define B_ 16
#define S_ 256
#define H_ 768
#define NH_ 12
#define DH_ 64
#define L_ 12
#define FF_ 3072
#define T_ 9
#define NTOK (B_*S_)

typedef __attribute__((ext_vector_type(8))) short bfrag;
typedef __attribute__((ext_vector_type(4))) float f4;

// round-to-nearest-even fp32 -> bf16 (values here are small; no inf/nan concerns)
__device__ inline unsigned short f2bf(float x) {
    unsigned u = __builtin_bit_cast(unsigned, x);
    return (unsigned short)((u + 0x7fffu + ((u >> 16) & 1u)) >> 16);
}
__device__ inline float bf2f(unsigned short h) {
    unsigned u = ((unsigned)h) << 16;
    return __builtin_bit_cast(float, u);
}

// ---------------- embedding + LN ----------------
__global__ __launch_bounds__(256) void k_embed_ln(
    const int* __restrict__ ids, const float* __restrict__ wemb,
    const float* __restrict__ pemb, const float* __restrict__ temb,
    const float* __restrict__ g, const float* __restrict__ b,
    float* __restrict__ out)
{
    int tok = blockIdx.x;
    int s = tok & (S_ - 1);
    int id = ids[tok];
    __shared__ float buf[H_];
    __shared__ float red[256];
    int tid = threadIdx.x;
    float acc = 0.f;
    for (int i = tid; i < H_; i += 256) {
        float v = wemb[(size_t)id * H_ + i] + pemb[(size_t)s * H_ + i] + temb[i];
        buf[i] = v; acc += v;
    }
    red[tid] = acc; __syncthreads();
    for (int o = 128; o > 0; o >>= 1) { if (tid < o) red[tid] += red[tid + o]; __syncthreads(); }
    float mean = red[0] * (1.0f / H_);
    __syncthreads();
    float vs = 0.f;
    for (int i = tid; i < H_; i += 256) { float d = buf[i] - mean; vs += d * d; }
    red[tid] = vs; __syncthreads();
    for (int o = 128; o > 0; o >>= 1) { if (tid < o) red[tid] += red[tid + o]; __syncthreads(); }
    float inv = 1.0f / sqrtf(red[0] * (1.0f / H_) + 1e-12f);
    for (int i = tid; i < H_; i += 256)
        out[(size_t)tok * H_ + i] = (buf[i] - mean) * inv * g[i] + b[i];
}

// ---------------- residual + LN ----------------
__global__ __launch_bounds__(256) void k_residual_ln(
    const float* __restrict__ x, const float* __restrict__ res,
    const float* __restrict__ g, const float* __restrict__ b,
    float* __restrict__ out)
{
    int tok = blockIdx.x;
    __shared__ float buf[H_];
    __shared__ float red[256];
    const float* xr = x + (size_t)tok * H_;
    const float* rr = res + (size_t)tok * H_;
    int tid = threadIdx.x;
    float acc = 0.f;
    for (int i = tid; i < H_; i += 256) { float v = xr[i] + rr[i]; buf[i] = v; acc += v; }
    red[tid] = acc; __syncthreads();
    for (int o = 128; o > 0; o >>= 1) { if (tid < o) red[tid] += red[tid + o]; __syncthreads(); }
    float mean = red[0] * (1.0f / H_);
    __syncthreads();
    float vs = 0.f;
    for (int i = tid; i < H_; i += 256) { float d = buf[i] - mean; vs += d * d; }
    red[tid] = vs; __syncthreads();
    for (int o = 128; o > 0; o >>= 1) { if (tid < o) red[tid] += red[tid + o]; __syncthreads(); }
    float inv = 1.0f / sqrtf(red[0] * (1.0f / H_) + 1e-12f);
    for (int i = tid; i < H_; i += 256)
        out[(size_t)tok * H_ + i] = (buf[i] - mean) * inv * g[i] + b[i];
}

// ---------------- MFMA GEMM with split-bf16 (hi/lo) fp32 emulation ----------------
// C = A(MxK,f32) @ W(KxN,f32) + bias, optional exact GELU.
// 128x128 block tile, BK=32, 4 waves (2x2), each wave 64x64 (4x4 frags of 16x16x32).
// a*b ~= ah*bh + ah*bl + al*bh  (error ~2^-17, fp32-class)
#define BM 128
#define BN 128
#define BK 32
#define LDK 40   // padded row length in bf16 elems (80B rows -> conflict-light)

__global__ __launch_bounds__(256) void k_gemm_mfma(
    const float* __restrict__ A, const float* __restrict__ W,
    const float* __restrict__ bias, float* __restrict__ C,
    int M, int N, int K, int act)
{
    __shared__ unsigned short Ah[BM * LDK];
    __shared__ unsigned short Al[BM * LDK];
    __shared__ unsigned short Bh[BN * LDK];
    __shared__ unsigned short Bl[BN * LDK];

    int tid = threadIdx.x;
    int m0 = blockIdx.y * BM;
    int n0 = blockIdx.x * BN;
    int lane = tid & 63;
    int wid = tid >> 6;
    int wm = wid >> 1, wn = wid & 1;       // 2x2 wave grid, 64x64 per wave
    int fr = lane & 15, fq = lane >> 4;    // fragment row/col + k-block

    f4 acc[4][4];
    #pragma unroll
    for (int i = 0; i < 4; i++)
        #pragma unroll
        for (int j = 0; j < 4; j++) acc[i][j] = (f4){0.f, 0.f, 0.f, 0.f};

    // staging indices
    int am = tid >> 1;                 // A: row
    int ak = (tid & 1) * 16;           // A: k-chunk base
    int bn = tid & 127;                // B: col
    int bk = (tid >> 7) * 16;          // B: k-chunk base

    for (int k0 = 0; k0 < K; k0 += BK) {
        // ---- stage A tile (BM x BK) : f32 -> hi/lo bf16 in LDS ----
        {
            const float* src = A + (size_t)(m0 + am) * K + k0 + ak;
            #pragma unroll
            for (int j = 0; j < 4; j++) {
                float4 v = reinterpret_cast<const float4*>(src)[j];
                ushort4 h, l;
                h.x = f2bf(v.x); l.x = f2bf(v.x - bf2f(h.x));
                h.y = f2bf(v.y); l.y = f2bf(v.y - bf2f(h.y));
                h.z = f2bf(v.z); l.z = f2bf(v.z - bf2f(h.z));
                h.w = f2bf(v.w); l.w = f2bf(v.w - bf2f(h.w));
                *reinterpret_cast<ushort4*>(&Ah[am * LDK + ak + 4 * j]) = h;
                *reinterpret_cast<ushort4*>(&Al[am * LDK + ak + 4 * j]) = l;
            }
        }
        // ---- stage B tile (BK x BN) transposed into [n][k] ----
        {
            const float* src = W + (size_t)(k0 + bk) * N + n0 + bn;
            float vv[16];
            #pragma unroll
            for (int kk = 0; kk < 16; kk++) vv[kk] = src[(size_t)kk * N];
            #pragma unroll
            for (int j = 0; j < 4; j++) {
                ushort4 h, l;
                h.x = f2bf(vv[4*j+0]); l.x = f2bf(vv[4*j+0] - bf2f(h.x));
                h.y = f2bf(vv[4*j+1]); l.y = f2bf(vv[4*j+1] - bf2f(h.y));
                h.z = f2bf(vv[4*j+2]); l.z = f2bf(vv[4*j+2] - bf2f(h.z));
                h.w = f2bf(vv[4*j+3]); l.w = f2bf(vv[4*j+3] - bf2f(h.w));
                *reinterpret_cast<ushort4*>(&Bh[bn * LDK + bk + 4 * j]) = h;
                *reinterpret_cast<ushort4*>(&Bl[bn * LDK + bk + 4 * j]) = l;
            }
        }
        __syncthreads();

        // ---- fragments + MFMA ----
        bfrag ah[4], al[4], bh[4], bl[4];
        #pragma unroll
        for (int mi = 0; mi < 4; mi++) {
            int row = wm * 64 + mi * 16 + fr;
            ah[mi] = *reinterpret_cast<const bfrag*>(&Ah[row * LDK + fq * 8]);
            al[mi] = *reinterpret_cast<const bfrag*>(&Al[row * LDK + fq * 8]);
        }
        #pragma unroll
        for (int ni = 0; ni < 4; ni++) {
            int col = wn * 64 + ni * 16 + fr;
            bh[ni] = *reinterpret_cast<const bfrag*>(&Bh[col * LDK + fq * 8]);
            bl[ni] = *reinterpret_cast<const bfrag*>(&Bl[col * LDK + fq * 8]);
        }
        #pragma unroll
        for (int mi = 0; mi < 4; mi++) {
            #pragma unroll
            for (int ni = 0; ni < 4; ni++) {
                acc[mi][ni] = __builtin_amdgcn_mfma_f32_16x16x32_bf16(ah[mi], bh[ni], acc[mi][ni], 0, 0, 0);
                acc[mi][ni] = __builtin_amdgcn_mfma_f32_16x16x32_bf16(ah[mi], bl[ni], acc[mi][ni], 0, 0, 0);
                acc[mi][ni] = __builtin_amdgcn_mfma_f32_16x16x32_bf16(al[mi], bh[ni], acc[mi][ni], 0, 0, 0);
            }
        }
        __syncthreads();
    }

    // ---- epilogue: bias (+ exact GELU), fp32 store ----
    #pragma unroll
    for (int mi = 0; mi < 4; mi++) {
        #pragma unroll
        for (int ni = 0; ni < 4; ni++) {
            int col = n0 + wn * 64 + ni * 16 + fr;
            float bv = bias[col];
            #pragma unroll
            for (int r = 0; r < 4; r++) {
                int row = m0 + wm * 64 + mi * 16 + fq * 4 + r;
                float v = acc[mi][ni][r] + bv;
                if (act == 1) v = 0.5f * v * (1.0f + erff(v * 0.70710678118654752f));
                C[(size_t)row * N + col] = v;
            }
        }
    }
}

// ---------------- attention scores + softmax ----------------
__global__ __launch_bounds__(256) void k_attn_scores(
    const float* __restrict__ Q, const float* __restrict__ Kb,
    const int* __restrict__ amask, float* __restrict__ att)
{
    int idx = blockIdx.x;
    int qpos = idx & (S_ - 1);
    int h = (idx >> 8) % NH_;
    int b = idx / (NH_ * S_);
    __shared__ float qv[DH_];
    __shared__ float red[256];
    int tid = threadIdx.x;
    const float* qp = Q + ((size_t)(b * S_ + qpos)) * H_ + h * DH_;
    if (tid < DH_) qv[tid] = qp[tid];
    __syncthreads();
    const float* kp = Kb + ((size_t)(b * S_ + tid)) * H_ + h * DH_;
    float dot = 0.f;
    #pragma unroll 8
    for (int d = 0; d < DH_; d++) dot = fmaf(qv[d], kp[d], dot);
    float sbias = (amask[b * S_ + tid] == 0) ? -1e9f : 0.f;
    float sc = dot * 0.125f + sbias;
    red[tid] = sc; __syncthreads();
    for (int o = 128; o > 0; o >>= 1) { if (tid < o) red[tid] = fmaxf(red[tid], red[tid + o]); __syncthreads(); }
    float mx = red[0]; __syncthreads();
    float e = expf(sc - mx);
    red[tid] = e; __syncthreads();
    for (int o = 128; o > 0; o >>= 1) { if (tid < o) red[tid] += red[tid + o]; __syncthreads(); }
    float p = e / red[0];
    att[((size_t)((b * NH_ + h) * S_ + qpos)) * S_ + tid] = p;
}

// ---------------- ctx = att @ V ----------------
__global__ __launch_bounds__(64) void k_attn_ctx(
    const float* __restrict__ att, const float* __restrict__ V,
    float* __restrict__ ctx)
{
    int idx = blockIdx.x;
    int qpos = idx & (S_ - 1);
    int h = (idx >> 8) % NH_;
    int b = idx / (NH_ * S_);
    int d = threadIdx.x;
    const float* ap = att + ((size_t)((b * NH_ + h) * S_ + qpos)) * S_;
    const float* vp = V + ((size_t)(b * S_)) * H_ + h * DH_ + d;
    float s = 0.f;
    #pragma unroll 4
    for (int k = 0; k < S_; k++) s = fmaf(ap[k], vp[(size_t)k * H_], s);
    ctx[((size_t)(b * S_ + qpos)) * H_ + h * DH_ + d] = s;
}

// ---------------- classifier: logits = h @ cls_W(768x9) + cls_b ----------------
__global__ __launch_bounds__(64) void k_classifier(
    const float* __restrict__ Hs, const float* __restrict__ Wc,
    const float* __restrict__ bc, float* __restrict__ logits)
{
    int tok = blockIdx.x;
    int lane = threadIdx.x;
    const float* hr = Hs + (size_t)tok * H_;
    float acc[T_];
    #pragma unroll
    for (int j = 0; j < T_; j++) acc[j] = 0.f;
    for (int k = lane; k < H_; k += 64) {
        float hv = hr[k];
        const float* wr = Wc + (size_t)k * T_;
        #pragma unroll
        for (int j = 0; j < T_; j++) acc[j] = fmaf(hv, wr[j], acc[j]);
    }
    #pragma unroll
    for (int j = 0; j < T_; j++) {
        float v = acc[j];
        for (int o = 32; o > 0; o >>= 1) v += __shfl_down(v, o);
        if (lane == 0) logits[(size_t)tok * T_ + j] = v + bc[j];
    }
}

// ---------------- CRF negative log-likelihood (loss) ----------------
__global__ __launch_bounds__(256) void k_crf_loss(
    const float* __restrict__ logits, const int* __restrict__ amask,
    const int* __restrict__ labels, const float* __restrict__ start,
    const float* __restrict__ endv, const float* __restrict__ trans,
    float* __restrict__ out_loss)
{
    __shared__ float score[B_][T_];
    __shared__ float nxt[B_][T_];
    __shared__ float res[B_];
    __shared__ int len_s[B_];
    int tid = threadIdx.x;
    if (tid < B_) {
        int l = 0;
        for (int s = 0; s < S_; s++) l += amask[tid * S_ + s];
        len_s[tid] = l;
    }
    __syncthreads();
    int b = tid / T_, j = tid % T_;
    if (tid < B_ * T_)
        score[b][j] = start[j] + logits[((size_t)(b * S_ + 1)) * T_ + j];
    __syncthreads();
    for (int s = 2; s < S_; s++) {
        if (tid < B_ * T_) {
            int len = len_s[b];
            int mt = (amask[b * S_ + s] != 0) && (s != len - 1);
            float mx = -1e30f;
            #pragma unroll
            for (int i = 0; i < T_; i++) mx = fmaxf(mx, score[b][i] + trans[i * T_ + j]);
            float sum = 0.f;
            #pragma unroll
            for (int i = 0; i < T_; i++) sum += expf(score[b][i] + trans[i * T_ + j] - mx);
            float lse = mx + logf(sum) + logits[((size_t)(b * S_ + s)) * T_ + j];
            nxt[b][j] = mt ? lse : score[b][j];
        }
        __syncthreads();
        if (tid < B_ * T_) score[b][j] = nxt[b][j];
        __syncthreads();
    }
    if (tid < B_) {
        int bb = tid;
        int len = len_s[bb];
        int s1m = (amask[bb * S_ + 1] != 0) && (1 != len - 1);
        int tp = s1m ? labels[bb * S_ + 1] : 0;
        int msum = s1m ? 1 : 0;
        float num = start[tp] + logits[((size_t)(bb * S_ + 1)) * T_ + tp];
        for (int s = 2; s < S_; s++) {
            int mk = (amask[bb * S_ + s] != 0) && (s != len - 1);
            int tc = mk ? labels[bb * S_ + s] : 0;
            if (mk) {
                num += trans[tp * T_ + tc] + logits[((size_t)(bb * S_ + s)) * T_ + tc];
                msum++;
            }
            tp = tc;
        }
        int ls = msum;
        int mkl = (amask[bb * S_ + ls] != 0) && (ls != len - 1) && (ls > 0);
        int last_tag = mkl ? labels[bb * S_ + ls] : 0;
        num += endv[last_tag];
        float mx = -1e30f;
        #pragma unroll
        for (int jj = 0; jj < T_; jj++) mx = fmaxf(mx, score[bb][jj] + endv[jj]);
        float sum = 0.f;
        #pragma unroll
        for (int jj = 0; jj < T_; jj++) sum += expf(score[bb][jj] + endv[jj] - mx);
        float den = mx + logf(sum);
        res[bb] = den - num;
    }
    __syncthreads();
    if (tid == 0) {
        float tot = 0.f;
        for (int bb = 0; bb < B_; bb++) tot += res[bb];
        out_loss[0] = tot;
    }
}

// ---------------- Viterbi decode ----------------
__global__ __launch_bounds__(64) void k_viterbi(
    const float* __restrict__ logits, const float* __restrict__ start,
    const float* __restrict__ endv, const float* __restrict__ trans,
    float* __restrict__ tags_out)
{
    int b = blockIdx.x;
    int tid = threadIdx.x;
    __shared__ float score[T_], nxt[T_];
    __shared__ unsigned char hist[S_ - 1][T_];
    if (tid < T_) score[tid] = start[tid] + logits[((size_t)(b * S_)) * T_ + tid];
    __syncthreads();
    for (int t = 1; t < S_; t++) {
        if (tid < T_) {
            int j = tid;
            float best = -1e30f; int bi = 0;
            #pragma unroll
            for (int i = 0; i < T_; i++) {
                float c = score[i] + trans[i * T_ + j];
                if (c > best) { best = c; bi = i; }
            }
            nxt[j] = best + logits[((size_t)(b * S_ + t)) * T_ + j];
            hist[t - 1][j] = (unsigned char)bi;
        }
        __syncthreads();
        if (tid < T_) score[tid] = nxt[tid];
        __syncthreads();
    }
    if (tid == 0) {
        float best = -1e30f; int last = 0;
        for (int j = 0; j < T_; j++) {
            float c = score[j] + endv[j];
            if (c > best) { best = c; last = j; }
        }
        tags_out[b * S_ + (S_ - 1)] = (float)last;
        int cur = last;
        for (int t = S_ - 2; t >= 0; t--) {
            cur = hist[t][cur];
            tags_out[b * S_ + t] = (float)cur;
        }
    }
}

// ---------------- driver ----------------
extern "C" void kernel_launch(void* const* d_in, const int* in_sizes, int n_in,
                              void* d_out, int out_size, void* d_ws, size_t ws_size,
                              hipStream_t stream)
{
    const int*   input_ids = (const int*)d_in[0];
    const int*   amask     = (const int*)d_in[1];
    const int*   labels    = (const int*)d_in[2];
    const float* word_emb  = (const float*)d_in[3];
    const float* pos_emb   = (const float*)d_in[4];
    const float* type_emb  = (const float*)d_in[5];
    const float* emb_g     = (const float*)d_in[6];
    const float* emb_b     = (const float*)d_in[7];
    const float* lWq = (const float*)d_in[8];
    const float* lbq = (const float*)d_in[9];
    const float* lWk = (const float*)d_in[10];
    const float* lbk = (const float*)d_in[11];
    const float* lWv = (const float*)d_in[12];
    const float* lbv = (const float*)d_in[13];
    const float* lWo = (const float*)d_in[14];
    const float* lbo = (const float*)d_in[15];
    const float* lg1 = (const float*)d_in[16];
    const float* lb1 = (const float*)d_in[17];
    const float* lWi = (const float*)d_in[18];
    const float* lbi = (const float*)d_in[19];
    const float* lWf = (const float*)d_in[20];
    const float* lbf = (const float*)d_in[21];
    const float* lg2 = (const float*)d_in[22];
    const float* lb2 = (const float*)d_in[23];
    const float* cls_W = (const float*)d_in[24];
    const float* cls_b = (const float*)d_in[25];
    const float* crf_start = (const float*)d_in[26];
    const float* crf_end   = (const float*)d_in[27];
    const float* crf_trans = (const float*)d_in[28];

    float* out = (float*)d_out;

    float* ws = (float*)d_ws;
    size_t off = 0;
    auto alloc = [&](size_t n) { float* p = ws + off; off += n; return p; };
    float* h    = alloc((size_t)NTOK * H_);
    float* q    = alloc((size_t)NTOK * H_);
    float* kbuf = alloc((size_t)NTOK * H_);
    float* v    = alloc((size_t)NTOK * H_);
    float* ctx  = alloc((size_t)NTOK * H_);
    float* tmp  = alloc((size_t)NTOK * H_);
    float* big  = alloc((size_t)NTOK * FF_);  // shared: att scores and FF activations
    float* logits = alloc((size_t)NTOK * T_);

    k_embed_ln<<<NTOK, 256, 0, stream>>>(input_ids, word_emb, pos_emb, type_emb, emb_g, emb_b, h);

    dim3 gHH(H_ / BN, NTOK / BM);
    dim3 gFF1(FF_ / BN, NTOK / BM);
    dim3 gFF2(H_ / BN, NTOK / BM);

    for (int l = 0; l < L_; l++) {
        const float* Wq = lWq + (size_t)l * H_ * H_;
        const float* bq = lbq + (size_t)l * H_;
        const float* Wk = lWk + (size_t)l * H_ * H_;
        const float* bk = lbk + (size_t)l * H_;
        const float* Wv = lWv + (size_t)l * H_ * H_;
        const float* bv = lbv + (size_t)l * H_;
        const float* Wo = lWo + (size_t)l * H_ * H_;
        const float* bo = lbo + (size_t)l * H_;
        const float* g1 = lg1 + (size_t)l * H_;
        const float* b1 = lb1 + (size_t)l * H_;
        const float* Wi = lWi + (size_t)l * H_ * FF_;
        const float* bi = lbi + (size_t)l * FF_;
        const float* Wf = lWf + (size_t)l * FF_ * H_;
        const float* bf = lbf + (size_t)l * H_;
        const float* g2 = lg2 + (size_t)l * H_;
        const float* b2 = lb2 + (size_t)l * H_;

        k_gemm_mfma<<<gHH, 256, 0, stream>>>(h, Wq, bq, q,    NTOK, H_, H_, 0);
        k_gemm_mfma<<<gHH, 256, 0, stream>>>(h, Wk, bk, kbuf, NTOK, H_, H_, 0);
        k_gemm_mfma<<<gHH, 256, 0, stream>>>(h, Wv, bv, v,    NTOK, H_, H_, 0);

        k_attn_scores<<<B_ * NH_ * S_, 256, 0, stream>>>(q, kbuf, amask, big);
        k_attn_ctx<<<B_ * NH_ * S_, 64, 0, stream>>>(big, v, ctx);

        k_gemm_mfma<<<gHH, 256, 0, stream>>>(ctx, Wo, bo, tmp, NTOK, H_, H_, 0);
        k_residual_ln<<<NTOK, 256, 0, stream>>>(tmp, h, g1, b1, h);

        k_gemm_mfma<<<gFF1, 256, 0, stream>>>(h, Wi, bi, big, NTOK, FF_, H_, 1);
        k_gemm_mfma<<<gFF2, 256, 0, stream>>>(big, Wf, bf, tmp, NTOK, H_, FF_, 0);
        k_residual_ln<<<NTOK, 256, 0, stream>>>(tmp, h, g2, b2, h);
    }

    k_classifier<<<NTOK, 64, 0, stream>>>(h, cls_W, cls_b, logits);
    k_crf_loss<<<1, 256, 0, stream>>>(logits, amask, labels, crf_start, crf_end, crf_trans, out);
    k_viterbi<<<B_, 64, 0, stream>>>(logits, crf_start, crf_end, crf_trans, out + 1);
}

// Round 5
// 6472.811 us; speedup vs baseline: 3.9126x; 2.0794x over previous
//
#include <hip/hip_runtime.h>

#define B_ 16
#define S_ 256
#define H_ 768
#define NH_ 12
#define DH_ 64
#define L_ 12
#define FF_ 3072
#define T_ 9
#define NTOK (B_*S_)

typedef __attribute__((ext_vector_type(8))) short bfrag;
typedef __attribute__((ext_vector_type(4))) float f4;

// round-to-nearest-even fp32 -> bf16
__device__ inline unsigned short f2bf(float x) {
    unsigned u = __builtin_bit_cast(unsigned, x);
    return (unsigned short)((u + 0x7fffu + ((u >> 16) & 1u)) >> 16);
}
__device__ inline float bf2f(unsigned short h) {
    unsigned u = ((unsigned)h) << 16;
    return __builtin_bit_cast(float, u);
}

// ---------------- embedding + LN ----------------
__global__ __launch_bounds__(256) void k_embed_ln(
    const int* __restrict__ ids, const float* __restrict__ wemb,
    const float* __restrict__ pemb, const float* __restrict__ temb,
    const float* __restrict__ g, const float* __restrict__ b,
    float* __restrict__ out)
{
    int tok = blockIdx.x;
    int s = tok & (S_ - 1);
    int id = ids[tok];
    __shared__ float buf[H_];
    __shared__ float red[256];
    int tid = threadIdx.x;
    float acc = 0.f;
    for (int i = tid; i < H_; i += 256) {
        float v = wemb[(size_t)id * H_ + i] + pemb[(size_t)s * H_ + i] + temb[i];
        buf[i] = v; acc += v;
    }
    red[tid] = acc; __syncthreads();
    for (int o = 128; o > 0; o >>= 1) { if (tid < o) red[tid] += red[tid + o]; __syncthreads(); }
    float mean = red[0] * (1.0f / H_);
    __syncthreads();
    float vs = 0.f;
    for (int i = tid; i < H_; i += 256) { float d = buf[i] - mean; vs += d * d; }
    red[tid] = vs; __syncthreads();
    for (int o = 128; o > 0; o >>= 1) { if (tid < o) red[tid] += red[tid + o]; __syncthreads(); }
    float inv = 1.0f / sqrtf(red[0] * (1.0f / H_) + 1e-12f);
    for (int i = tid; i < H_; i += 256)
        out[(size_t)tok * H_ + i] = (buf[i] - mean) * inv * g[i] + b[i];
}

// ---------------- residual + LN ----------------
__global__ __launch_bounds__(256) void k_residual_ln(
    const float* __restrict__ x, const float* __restrict__ res,
    const float* __restrict__ g, const float* __restrict__ b,
    float* __restrict__ out)
{
    int tok = blockIdx.x;
    __shared__ float buf[H_];
    __shared__ float red[256];
    const float* xr = x + (size_t)tok * H_;
    const float* rr = res + (size_t)tok * H_;
    int tid = threadIdx.x;
    float acc = 0.f;
    for (int i = tid; i < H_; i += 256) { float v = xr[i] + rr[i]; buf[i] = v; acc += v; }
    red[tid] = acc; __syncthreads();
    for (int o = 128; o > 0; o >>= 1) { if (tid < o) red[tid] += red[tid + o]; __syncthreads(); }
    float mean = red[0] * (1.0f / H_);
    __syncthreads();
    float vs = 0.f;
    for (int i = tid; i < H_; i += 256) { float d = buf[i] - mean; vs += d * d; }
    red[tid] = vs; __syncthreads();
    for (int o = 128; o > 0; o >>= 1) { if (tid < o) red[tid] += red[tid + o]; __syncthreads(); }
    float inv = 1.0f / sqrtf(red[0] * (1.0f / H_) + 1e-12f);
    for (int i = tid; i < H_; i += 256)
        out[(size_t)tok * H_ + i] = (buf[i] - mean) * inv * g[i] + b[i];
}

// ---------------- MFMA GEMM with split-bf16 (hi/lo) fp32 emulation ----------------
#define BM 128
#define BN 128
#define BK 32
#define LDK 40

__global__ __launch_bounds__(256) void k_gemm_mfma(
    const float* __restrict__ A, const float* __restrict__ W,
    const float* __restrict__ bias, float* __restrict__ C,
    int M, int N, int K, int act)
{
    __shared__ unsigned short Ah[BM * LDK];
    __shared__ unsigned short Al[BM * LDK];
    __shared__ unsigned short Bh[BN * LDK];
    __shared__ unsigned short Bl[BN * LDK];

    int tid = threadIdx.x;
    int m0 = blockIdx.y * BM;
    int n0 = blockIdx.x * BN;
    int lane = tid & 63;
    int wid = tid >> 6;
    int wm = wid >> 1, wn = wid & 1;
    int fr = lane & 15, fq = lane >> 4;

    f4 acc[4][4];
    #pragma unroll
    for (int i = 0; i < 4; i++)
        #pragma unroll
        for (int j = 0; j < 4; j++) acc[i][j] = (f4){0.f, 0.f, 0.f, 0.f};

    int am = tid >> 1;
    int ak = (tid & 1) * 16;
    int bn = tid & 127;
    int bk = (tid >> 7) * 16;

    for (int k0 = 0; k0 < K; k0 += BK) {
        {
            const float* src = A + (size_t)(m0 + am) * K + k0 + ak;
            #pragma unroll
            for (int j = 0; j < 4; j++) {
                float4 v = reinterpret_cast<const float4*>(src)[j];
                ushort4 h, l;
                h.x = f2bf(v.x); l.x = f2bf(v.x - bf2f(h.x));
                h.y = f2bf(v.y); l.y = f2bf(v.y - bf2f(h.y));
                h.z = f2bf(v.z); l.z = f2bf(v.z - bf2f(h.z));
                h.w = f2bf(v.w); l.w = f2bf(v.w - bf2f(h.w));
                *reinterpret_cast<ushort4*>(&Ah[am * LDK + ak + 4 * j]) = h;
                *reinterpret_cast<ushort4*>(&Al[am * LDK + ak + 4 * j]) = l;
            }
        }
        {
            const float* src = W + (size_t)(k0 + bk) * N + n0 + bn;
            float vv[16];
            #pragma unroll
            for (int kk = 0; kk < 16; kk++) vv[kk] = src[(size_t)kk * N];
            #pragma unroll
            for (int j = 0; j < 4; j++) {
                ushort4 h, l;
                h.x = f2bf(vv[4*j+0]); l.x = f2bf(vv[4*j+0] - bf2f(h.x));
                h.y = f2bf(vv[4*j+1]); l.y = f2bf(vv[4*j+1] - bf2f(h.y));
                h.z = f2bf(vv[4*j+2]); l.z = f2bf(vv[4*j+2] - bf2f(h.z));
                h.w = f2bf(vv[4*j+3]); l.w = f2bf(vv[4*j+3] - bf2f(h.w));
                *reinterpret_cast<ushort4*>(&Bh[bn * LDK + bk + 4 * j]) = h;
                *reinterpret_cast<ushort4*>(&Bl[bn * LDK + bk + 4 * j]) = l;
            }
        }
        __syncthreads();

        bfrag ah[4], al[4], bh[4], bl[4];
        #pragma unroll
        for (int mi = 0; mi < 4; mi++) {
            int row = wm * 64 + mi * 16 + fr;
            ah[mi] = *reinterpret_cast<const bfrag*>(&Ah[row * LDK + fq * 8]);
            al[mi] = *reinterpret_cast<const bfrag*>(&Al[row * LDK + fq * 8]);
        }
        #pragma unroll
        for (int ni = 0; ni < 4; ni++) {
            int col = wn * 64 + ni * 16 + fr;
            bh[ni] = *reinterpret_cast<const bfrag*>(&Bh[col * LDK + fq * 8]);
            bl[ni] = *reinterpret_cast<const bfrag*>(&Bl[col * LDK + fq * 8]);
        }
        #pragma unroll
        for (int mi = 0; mi < 4; mi++) {
            #pragma unroll
            for (int ni = 0; ni < 4; ni++) {
                acc[mi][ni] = __builtin_amdgcn_mfma_f32_16x16x32_bf16(ah[mi], bh[ni], acc[mi][ni], 0, 0, 0);
                acc[mi][ni] = __builtin_amdgcn_mfma_f32_16x16x32_bf16(ah[mi], bl[ni], acc[mi][ni], 0, 0, 0);
                acc[mi][ni] = __builtin_amdgcn_mfma_f32_16x16x32_bf16(al[mi], bh[ni], acc[mi][ni], 0, 0, 0);
            }
        }
        __syncthreads();
    }

    #pragma unroll
    for (int mi = 0; mi < 4; mi++) {
        #pragma unroll
        for (int ni = 0; ni < 4; ni++) {
            int col = n0 + wn * 64 + ni * 16 + fr;
            float bv = bias[col];
            #pragma unroll
            for (int r = 0; r < 4; r++) {
                int row = m0 + wm * 64 + mi * 16 + fq * 4 + r;
                float v = acc[mi][ni][r] + bv;
                if (act == 1) v = 0.5f * v * (1.0f + erff(v * 0.70710678118654752f));
                C[(size_t)row * N + col] = v;
            }
        }
    }
}

// ---------------- fused flash attention (split-bf16, fp32-class accuracy) ----------------
// grid = B * NH * 4 ; block = 256 (4 waves); each wave: 16 q-rows; kv-tiles of 32
__global__ __launch_bounds__(256) void k_attn_fused(
    const float* __restrict__ Q, const float* __restrict__ Kb,
    const float* __restrict__ V, const int* __restrict__ amask,
    float* __restrict__ ctx)
{
    __shared__ unsigned short Kh[32][88], Kl[32][88];     // [kv][d]
    __shared__ unsigned short Vh[64][40], Vl[64][40];     // [d][kv]  (transposed)
    __shared__ unsigned short Ph[4][16][40], Pl[4][16][40]; // per-wave [qrow][kv]

    int idx = blockIdx.x;
    int qt = idx & 3;
    int hd = (idx >> 2) % NH_;
    int b = idx / (4 * NH_);
    int tid = threadIdx.x;
    int lane = tid & 63, wid = tid >> 6;
    int fr = lane & 15, fq = lane >> 4;

    int q0 = qt * 64 + wid * 16;

    // Q fragments (rows q0+fr, k = ks*32 + fq*8 + j), hi/lo
    bfrag qh[2], ql[2];
    {
        const float* qbase = Q + ((size_t)(b * S_ + q0 + fr)) * H_ + hd * DH_;
        #pragma unroll
        for (int ks = 0; ks < 2; ks++) {
            const float4* p = reinterpret_cast<const float4*>(qbase + ks * 32 + fq * 8);
            float4 v0 = p[0], v1 = p[1];
            float vv[8] = {v0.x, v0.y, v0.z, v0.w, v1.x, v1.y, v1.z, v1.w};
            #pragma unroll
            for (int j = 0; j < 8; j++) {
                unsigned short h = f2bf(vv[j]);
                qh[ks][j] = (short)h;
                ql[ks][j] = (short)f2bf(vv[j] - bf2f(h));
            }
        }
    }

    f4 o[4];
    #pragma unroll
    for (int i = 0; i < 4; i++) o[i] = (f4){0.f, 0.f, 0.f, 0.f};
    float m[4], l[4];
    #pragma unroll
    for (int r = 0; r < 4; r++) { m[r] = -3e38f; l[r] = 0.f; }

    int kvrow = tid >> 3;             // 0..31
    int dbase = (tid & 7) * 8;        // 0..56

    for (int t = 0; t < 8; t++) {
        // ---- stage K tile (32 x 64) hi/lo ----
        {
            const float* src = Kb + ((size_t)(b * S_ + t * 32 + kvrow)) * H_ + hd * DH_ + dbase;
            float4 a4 = reinterpret_cast<const float4*>(src)[0];
            float4 b4 = reinterpret_cast<const float4*>(src)[1];
            float vv[8] = {a4.x, a4.y, a4.z, a4.w, b4.x, b4.y, b4.z, b4.w};
            ushort4 h0, l0, h1, l1;
            h0.x = f2bf(vv[0]); l0.x = f2bf(vv[0] - bf2f(h0.x));
            h0.y = f2bf(vv[1]); l0.y = f2bf(vv[1] - bf2f(h0.y));
            h0.z = f2bf(vv[2]); l0.z = f2bf(vv[2] - bf2f(h0.z));
            h0.w = f2bf(vv[3]); l0.w = f2bf(vv[3] - bf2f(h0.w));
            h1.x = f2bf(vv[4]); l1.x = f2bf(vv[4] - bf2f(h1.x));
            h1.y = f2bf(vv[5]); l1.y = f2bf(vv[5] - bf2f(h1.y));
            h1.z = f2bf(vv[6]); l1.z = f2bf(vv[6] - bf2f(h1.z));
            h1.w = f2bf(vv[7]); l1.w = f2bf(vv[7] - bf2f(h1.w));
            *reinterpret_cast<ushort4*>(&Kh[kvrow][dbase]) = h0;
            *reinterpret_cast<ushort4*>(&Kh[kvrow][dbase + 4]) = h1;
            *reinterpret_cast<ushort4*>(&Kl[kvrow][dbase]) = l0;
            *reinterpret_cast<ushort4*>(&Kl[kvrow][dbase + 4]) = l1;
        }
        // ---- stage V tile transposed (d x kv) hi/lo ----
        {
            const float* src = V + ((size_t)(b * S_ + t * 32 + kvrow)) * H_ + hd * DH_ + dbase;
            float4 a4 = reinterpret_cast<const float4*>(src)[0];
            float4 b4 = reinterpret_cast<const float4*>(src)[1];
            float vv[8] = {a4.x, a4.y, a4.z, a4.w, b4.x, b4.y, b4.z, b4.w};
            #pragma unroll
            for (int j = 0; j < 8; j++) {
                unsigned short h = f2bf(vv[j]);
                Vh[dbase + j][kvrow] = h;
                Vl[dbase + j][kvrow] = f2bf(vv[j] - bf2f(h));
            }
        }
        __syncthreads();

        // ---- scores: S(16 x 32) = Q Kt^T ----
        f4 s0 = (f4){0.f,0.f,0.f,0.f}, s1 = (f4){0.f,0.f,0.f,0.f};
        #pragma unroll
        for (int ks = 0; ks < 2; ks++) {
            bfrag kbh0 = *reinterpret_cast<const bfrag*>(&Kh[fr][ks * 32 + fq * 8]);
            bfrag kbl0 = *reinterpret_cast<const bfrag*>(&Kl[fr][ks * 32 + fq * 8]);
            bfrag kbh1 = *reinterpret_cast<const bfrag*>(&Kh[16 + fr][ks * 32 + fq * 8]);
            bfrag kbl1 = *reinterpret_cast<const bfrag*>(&Kl[16 + fr][ks * 32 + fq * 8]);
            s0 = __builtin_amdgcn_mfma_f32_16x16x32_bf16(qh[ks], kbh0, s0, 0, 0, 0);
            s0 = __builtin_amdgcn_mfma_f32_16x16x32_bf16(qh[ks], kbl0, s0, 0, 0, 0);
            s0 = __builtin_amdgcn_mfma_f32_16x16x32_bf16(ql[ks], kbh0, s0, 0, 0, 0);
            s1 = __builtin_amdgcn_mfma_f32_16x16x32_bf16(qh[ks], kbh1, s1, 0, 0, 0);
            s1 = __builtin_amdgcn_mfma_f32_16x16x32_bf16(qh[ks], kbl1, s1, 0, 0, 0);
            s1 = __builtin_amdgcn_mfma_f32_16x16x32_bf16(ql[ks], kbh1, s1, 0, 0, 0);
        }

        // ---- online softmax over this 32-col tile ----
        float cb0 = (amask[b * S_ + t * 32 + fr] == 0) ? -1e9f : 0.f;
        float cb1 = (amask[b * S_ + t * 32 + 16 + fr] == 0) ? -1e9f : 0.f;
        float sc0[4], sc1[4], fct[4], pr0[4], pr1[4];
        #pragma unroll
        for (int r = 0; r < 4; r++) {
            sc0[r] = s0[r] * 0.125f + cb0;
            sc1[r] = s1[r] * 0.125f + cb1;
            float tm = fmaxf(sc0[r], sc1[r]);
            #pragma unroll
            for (int od = 1; od < 16; od <<= 1) tm = fmaxf(tm, __shfl_xor(tm, od));
            float mn = fmaxf(m[r], tm);
            fct[r] = expf(m[r] - mn);
            pr0[r] = expf(sc0[r] - mn);
            pr1[r] = expf(sc1[r] - mn);
            float rs = pr0[r] + pr1[r];
            #pragma unroll
            for (int od = 1; od < 16; od <<= 1) rs += __shfl_xor(rs, od);
            l[r] = l[r] * fct[r] + rs;
            m[r] = mn;
        }
        #pragma unroll
        for (int ci = 0; ci < 4; ci++)
            #pragma unroll
            for (int r = 0; r < 4; r++) o[ci][r] *= fct[r];

        // ---- P -> LDS (hi/lo), per-wave region ----
        #pragma unroll
        for (int r = 0; r < 4; r++) {
            int row = fq * 4 + r;
            unsigned short h0 = f2bf(pr0[r]);
            Ph[wid][row][fr] = h0;
            Pl[wid][row][fr] = f2bf(pr0[r] - bf2f(h0));
            unsigned short h1 = f2bf(pr1[r]);
            Ph[wid][row][16 + fr] = h1;
            Pl[wid][row][16 + fr] = f2bf(pr1[r] - bf2f(h1));
        }

        // ---- O += P @ V ----
        bfrag pah = *reinterpret_cast<const bfrag*>(&Ph[wid][fr][fq * 8]);
        bfrag pal = *reinterpret_cast<const bfrag*>(&Pl[wid][fr][fq * 8]);
        #pragma unroll
        for (int ci = 0; ci < 4; ci++) {
            bfrag vbh = *reinterpret_cast<const bfrag*>(&Vh[ci * 16 + fr][fq * 8]);
            bfrag vbl = *reinterpret_cast<const bfrag*>(&Vl[ci * 16 + fr][fq * 8]);
            o[ci] = __builtin_amdgcn_mfma_f32_16x16x32_bf16(pah, vbh, o[ci], 0, 0, 0);
            o[ci] = __builtin_amdgcn_mfma_f32_16x16x32_bf16(pah, vbl, o[ci], 0, 0, 0);
            o[ci] = __builtin_amdgcn_mfma_f32_16x16x32_bf16(pal, vbh, o[ci], 0, 0, 0);
        }
        __syncthreads();
    }

    // ---- epilogue: normalize and store ctx ----
    #pragma unroll
    for (int r = 0; r < 4; r++) {
        float inv = 1.0f / l[r];
        int row = b * S_ + q0 + fq * 4 + r;
        #pragma unroll
        for (int ci = 0; ci < 4; ci++)
            ctx[(size_t)row * H_ + hd * DH_ + ci * 16 + fr] = o[ci][r] * inv;
    }
}

// ---------------- classifier ----------------
__global__ __launch_bounds__(64) void k_classifier(
    const float* __restrict__ Hs, const float* __restrict__ Wc,
    const float* __restrict__ bc, float* __restrict__ logits)
{
    int tok = blockIdx.x;
    int lane = threadIdx.x;
    const float* hr = Hs + (size_t)tok * H_;
    float acc[T_];
    #pragma unroll
    for (int j = 0; j < T_; j++) acc[j] = 0.f;
    for (int k = lane; k < H_; k += 64) {
        float hv = hr[k];
        const float* wr = Wc + (size_t)k * T_;
        #pragma unroll
        for (int j = 0; j < T_; j++) acc[j] = fmaf(hv, wr[j], acc[j]);
    }
    #pragma unroll
    for (int j = 0; j < T_; j++) {
        float v = acc[j];
        for (int o = 32; o > 0; o >>= 1) v += __shfl_down(v, o);
        if (lane == 0) logits[(size_t)tok * T_ + j] = v + bc[j];
    }
}

// ---------------- CRF loss ----------------
__global__ __launch_bounds__(256) void k_crf_loss(
    const float* __restrict__ logits, const int* __restrict__ amask,
    const int* __restrict__ labels, const float* __restrict__ start,
    const float* __restrict__ endv, const float* __restrict__ trans,
    float* __restrict__ out_loss)
{
    __shared__ float score[B_][T_];
    __shared__ float nxt[B_][T_];
    __shared__ float res[B_];
    __shared__ int len_s[B_];
    int tid = threadIdx.x;
    if (tid < B_) {
        int l = 0;
        for (int s = 0; s < S_; s++) l += amask[tid * S_ + s];
        len_s[tid] = l;
    }
    __syncthreads();
    int b = tid / T_, j = tid % T_;
    if (tid < B_ * T_)
        score[b][j] = start[j] + logits[((size_t)(b * S_ + 1)) * T_ + j];
    __syncthreads();
    for (int s = 2; s < S_; s++) {
        if (tid < B_ * T_) {
            int len = len_s[b];
            int mt = (amask[b * S_ + s] != 0) && (s != len - 1);
            float mx = -1e30f;
            #pragma unroll
            for (int i = 0; i < T_; i++) mx = fmaxf(mx, score[b][i] + trans[i * T_ + j]);
            float sum = 0.f;
            #pragma unroll
            for (int i = 0; i < T_; i++) sum += expf(score[b][i] + trans[i * T_ + j] - mx);
            float lse = mx + logf(sum) + logits[((size_t)(b * S_ + s)) * T_ + j];
            nxt[b][j] = mt ? lse : score[b][j];
        }
        __syncthreads();
        if (tid < B_ * T_) score[b][j] = nxt[b][j];
        __syncthreads();
    }
    if (tid < B_) {
        int bb = tid;
        int len = len_s[bb];
        int s1m = (amask[bb * S_ + 1] != 0) && (1 != len - 1);
        int tp = s1m ? labels[bb * S_ + 1] : 0;
        int msum = s1m ? 1 : 0;
        float num = start[tp] + logits[((size_t)(bb * S_ + 1)) * T_ + tp];
        for (int s = 2; s < S_; s++) {
            int mk = (amask[bb * S_ + s] != 0) && (s != len - 1);
            int tc = mk ? labels[bb * S_ + s] : 0;
            if (mk) {
                num += trans[tp * T_ + tc] + logits[((size_t)(bb * S_ + s)) * T_ + tc];
                msum++;
            }
            tp = tc;
        }
        int ls = msum;
        int mkl = (amask[bb * S_ + ls] != 0) && (ls != len - 1) && (ls > 0);
        int last_tag = mkl ? labels[bb * S_ + ls] : 0;
        num += endv[last_tag];
        float mx = -1e30f;
        #pragma unroll
        for (int jj = 0; jj < T_; jj++) mx = fmaxf(mx, score[bb][jj] + endv[jj]);
        float sum = 0.f;
        #pragma unroll
        for (int jj = 0; jj < T_; jj++) sum += expf(score[bb][jj] + endv[jj] - mx);
        float den = mx + logf(sum);
        res[bb] = den - num;
    }
    __syncthreads();
    if (tid == 0) {
        float tot = 0.f;
        for (int bb = 0; bb < B_; bb++) tot += res[bb];
        out_loss[0] = tot;
    }
}

// ---------------- Viterbi ----------------
__global__ __launch_bounds__(64) void k_viterbi(
    const float* __restrict__ logits, const float* __restrict__ start,
    const float* __restrict__ endv, const float* __restrict__ trans,
    float* __restrict__ tags_out)
{
    int b = blockIdx.x;
    int tid = threadIdx.x;
    __shared__ float score[T_], nxt[T_];
    __shared__ unsigned char hist[S_ - 1][T_];
    if (tid < T_) score[tid] = start[tid] + logits[((size_t)(b * S_)) * T_ + tid];
    __syncthreads();
    for (int t = 1; t < S_; t++) {
        if (tid < T_) {
            int j = tid;
            float best = -1e30f; int bi = 0;
            #pragma unroll
            for (int i = 0; i < T_; i++) {
                float c = score[i] + trans[i * T_ + j];
                if (c > best) { best = c; bi = i; }
            }
            nxt[j] = best + logits[((size_t)(b * S_ + t)) * T_ + j];
            hist[t - 1][j] = (unsigned char)bi;
        }
        __syncthreads();
        if (tid < T_) score[tid] = nxt[tid];
        __syncthreads();
    }
    if (tid == 0) {
        float best = -1e30f; int last = 0;
        for (int j = 0; j < T_; j++) {
            float c = score[j] + endv[j];
            if (c > best) { best = c; last = j; }
        }
        tags_out[b * S_ + (S_ - 1)] = (float)last;
        int cur = last;
        for (int t = S_ - 2; t >= 0; t--) {
            cur = hist[t][cur];
            tags_out[b * S_ + t] = (float)cur;
        }
    }
}

// ---------------- driver ----------------
extern "C" void kernel_launch(void* const* d_in, const int* in_sizes, int n_in,
                              void* d_out, int out_size, void* d_ws, size_t ws_size,
                              hipStream_t stream)
{
    const int*   input_ids = (const int*)d_in[0];
    const int*   amask     = (const int*)d_in[1];
    const int*   labels    = (const int*)d_in[2];
    const float* word_emb  = (const float*)d_in[3];
    const float* pos_emb   = (const float*)d_in[4];
    const float* type_emb  = (const float*)d_in[5];
    const float* emb_g     = (const float*)d_in[6];
    const float* emb_b     = (const float*)d_in[7];
    const float* lWq = (const float*)d_in[8];
    const float* lbq = (const float*)d_in[9];
    const float* lWk = (const float*)d_in[10];
    const float* lbk = (const float*)d_in[11];
    const float* lWv = (const float*)d_in[12];
    const float* lbv = (const float*)d_in[13];
    const float* lWo = (const float*)d_in[14];
    const float* lbo = (const float*)d_in[15];
    const float* lg1 = (const float*)d_in[16];
    const float* lb1 = (const float*)d_in[17];
    const float* lWi = (const float*)d_in[18];
    const float* lbi = (const float*)d_in[19];
    const float* lWf = (const float*)d_in[20];
    const float* lbf = (const float*)d_in[21];
    const float* lg2 = (const float*)d_in[22];
    const float* lb2 = (const float*)d_in[23];
    const float* cls_W = (const float*)d_in[24];
    const float* cls_b = (const float*)d_in[25];
    const float* crf_start = (const float*)d_in[26];
    const float* crf_end   = (const float*)d_in[27];
    const float* crf_trans = (const float*)d_in[28];

    float* out = (float*)d_out;

    float* ws = (float*)d_ws;
    size_t off = 0;
    auto alloc = [&](size_t n) { float* p = ws + off; off += n; return p; };
    float* h    = alloc((size_t)NTOK * H_);
    float* q    = alloc((size_t)NTOK * H_);
    float* kbuf = alloc((size_t)NTOK * H_);
    float* v    = alloc((size_t)NTOK * H_);
    float* ctx  = alloc((size_t)NTOK * H_);
    float* tmp  = alloc((size_t)NTOK * H_);
    float* big  = alloc((size_t)NTOK * FF_);
    float* logits = alloc((size_t)NTOK * T_);

    k_embed_ln<<<NTOK, 256, 0, stream>>>(input_ids, word_emb, pos_emb, type_emb, emb_g, emb_b, h);

    dim3 gHH(H_ / BN, NTOK / BM);
    dim3 gFF1(FF_ / BN, NTOK / BM);
    dim3 gFF2(H_ / BN, NTOK / BM);

    for (int l = 0; l < L_; l++) {
        const float* Wq = lWq + (size_t)l * H_ * H_;
        const float* bq = lbq + (size_t)l * H_;
        const float* Wk = lWk + (size_t)l * H_ * H_;
        const float* bk = lbk + (size_t)l * H_;
        const float* Wv = lWv + (size_t)l * H_ * H_;
        const float* bv = lbv + (size_t)l * H_;
        const float* Wo = lWo + (size_t)l * H_ * H_;
        const float* bo = lbo + (size_t)l * H_;
        const float* g1 = lg1 + (size_t)l * H_;
        const float* b1 = lb1 + (size_t)l * H_;
        const float* Wi = lWi + (size_t)l * H_ * FF_;
        const float* bi = lbi + (size_t)l * FF_;
        const float* Wf = lWf + (size_t)l * FF_ * H_;
        const float* bf = lbf + (size_t)l * H_;
        const float* g2 = lg2 + (size_t)l * H_;
        const float* b2 = lb2 + (size_t)l * H_;

        k_gemm_mfma<<<gHH, 256, 0, stream>>>(h, Wq, bq, q,    NTOK, H_, H_, 0);
        k_gemm_mfma<<<gHH, 256, 0, stream>>>(h, Wk, bk, kbuf, NTOK, H_, H_, 0);
        k_gemm_mfma<<<gHH, 256, 0, stream>>>(h, Wv, bv, v,    NTOK, H_, H_, 0);

        k_attn_fused<<<B_ * NH_ * 4, 256, 0, stream>>>(q, kbuf, v, amask, ctx);

        k_gemm_mfma<<<gHH, 256, 0, stream>>>(ctx, Wo, bo, tmp, NTOK, H_, H_, 0);
        k_residual_ln<<<NTOK, 256, 0, stream>>>(tmp, h, g1, b1, h);

        k_gemm_mfma<<<gFF1, 256, 0, stream>>>(h, Wi, bi, big, NTOK, FF_, H_, 1);
        k_gemm_mfma<<<gFF2, 256, 0, stream>>>(big, Wf, bf, tmp, NTOK, H_, FF_, 0);
        k_residual_ln<<<NTOK, 256, 0, stream>>>(tmp, h, g2, b2, h);
    }

    k_classifier<<<NTOK, 64, 0, stream>>>(h, cls_W, cls_b, logits);
    k_crf_loss<<<1, 256, 0, stream>>>(logits, amask, labels, crf_start, crf_end, crf_trans, out);
    k_viterbi<<<B_, 64, 0, stream>>>(logits, crf_start, crf_end, crf_trans, out + 1);
}